// Round 2
// baseline (131.697 us; speedup 1.0000x reference)
//
#include <hip/hip_runtime.h>
#include <hip/hip_bf16.h>

// Problem constants (fixed by setup_inputs): B=32768, D=768, C=200.
#define NROWS 32768
#define DIMS  768
#define NC    200
#define CPAD  256   // pad centers to 256 with zero rows -> no column masking needed

typedef __attribute__((ext_vector_type(8))) short short8;  // 8 bf16 in 4 VGPRs
typedef __attribute__((ext_vector_type(4))) float f32x4;

__device__ __forceinline__ short f2bfs(float f) {
  // round-to-nearest-even f32 -> bf16 bits
  union { float f; unsigned u; } x; x.f = f;
  unsigned u = x.u;
  unsigned r = u + 0x7fffu + ((u >> 16) & 1u);
  return (short)(r >> 16);
}

// Kernel 1: L2-normalize centers, write bf16 [CPAD][DIMS]; rows >= NC are zeros.
__global__ __launch_bounds__(256) void prep_centers_k(const float* __restrict__ centers,
                                                      short* __restrict__ cnb) {
  const int c = blockIdx.x;
  const int tid = threadIdx.x;
  if (c >= NC) {
    for (int d = tid; d < DIMS; d += 256) cnb[c * DIMS + d] = 0;
    return;
  }
  float ssq = 0.f;
  for (int d = tid; d < DIMS; d += 256) {
    float v = centers[c * DIMS + d];
    ssq += v * v;
  }
#pragma unroll
  for (int off = 32; off > 0; off >>= 1) ssq += __shfl_down(ssq, off);
  __shared__ float red[4];
  const int wid = tid >> 6, lane = tid & 63;
  if (lane == 0) red[wid] = ssq;
  __syncthreads();
  const float tot = red[0] + red[1] + red[2] + red[3];
  const float inv = 1.f / fmaxf(sqrtf(tot), 1e-8f);
  for (int d = tid; d < DIMS; d += 256) cnb[c * DIMS + d] = f2bfs(centers[c * DIMS + d] * inv);
}

// Kernel 2: per wave: 16 feature rows x all 256 (padded) centers via MFMA.
// A frag (16x32 bf16): lane holds A[m][k], m = lane&15, k = (lane>>4)*8 + j.
// B frag (32x16 bf16): lane holds B[k][n], n = lane&15, k = (lane>>4)*8 + j.
//   (any k-permutation cancels since A and B use the same per-lane k indices)
// D frag: col = lane&15, row = (lane>>4)*4 + reg.  [verified mapping per guide §3]
__global__ __launch_bounds__(256) void cos_loss_k(
    const float* __restrict__ feats,
    const short* __restrict__ cnb,
    const int* __restrict__ labels,
    const int* __restrict__ labelled,     // bool shipped as int32 by harness
    float* __restrict__ out) {
  const int tid = threadIdx.x;
  const int wid = tid >> 6;
  const int lane = tid & 63;
  const int m = lane & 15;    // A-row / B-col selector within tile
  const int kg = lane >> 4;   // k-group 0..3
  const int rowBase = blockIdx.x * 64 + wid * 16;

  f32x4 acc[16];
#pragma unroll
  for (int t = 0; t < 16; ++t) acc[t] = (f32x4){0.f, 0.f, 0.f, 0.f};

  const float* fp = feats + (size_t)(rowBase + m) * DIMS + kg * 8;
  const short* bp = cnb + m * DIMS + kg * 8;

  float ssq = 0.f;
  for (int k0 = 0; k0 < DIMS; k0 += 32) {
    const float4 a0 = *(const float4*)(fp + k0);
    const float4 a1 = *(const float4*)(fp + k0 + 4);
    short8 af;
    af[0] = f2bfs(a0.x); af[1] = f2bfs(a0.y); af[2] = f2bfs(a0.z); af[3] = f2bfs(a0.w);
    af[4] = f2bfs(a1.x); af[5] = f2bfs(a1.y); af[6] = f2bfs(a1.z); af[7] = f2bfs(a1.w);
    ssq += a0.x * a0.x + a0.y * a0.y + a0.z * a0.z + a0.w * a0.w;
    ssq += a1.x * a1.x + a1.y * a1.y + a1.z * a1.z + a1.w * a1.w;
#pragma unroll
    for (int t = 0; t < 16; ++t) {
      const short8 bf = *(const short8*)(bp + (size_t)t * 16 * DIMS + k0);
      acc[t] = __builtin_amdgcn_mfma_f32_16x16x32_bf16(af, bf, acc[t], 0, 0, 0);
    }
  }

  // full-row ssq: combine the 4 k-groups that share the same row (lane&15)
  ssq += __shfl_xor(ssq, 16);
  ssq += __shfl_xor(ssq, 32);
  // redistribute to D-layout rows: this lane's D rows are kg*4 + r
  float inv[4];
#pragma unroll
  for (int r = 0; r < 4; ++r) {
    const float s = __shfl(ssq, kg * 4 + r);  // lane (kg*4+r) holds row (kg*4+r)'s ssq
    inv[r] = 1.f / fmaxf(sqrtf(s), 1e-8f);
  }

  int lab[4]; int lb[4];
#pragma unroll
  for (int r = 0; r < 4; ++r) {
    const int row = rowBase + kg * 4 + r;
    lab[r] = labels[row];
    lb[r] = labelled[row];
  }

  float l1[4] = {0.f, 0.f, 0.f, 0.f};
  float al[4] = {0.f, 0.f, 0.f, 0.f};
#pragma unroll
  for (int t = 0; t < 16; ++t) {
    const int col = t * 16 + m;
#pragma unroll
    for (int r = 0; r < 4; ++r) {
      const float a = fabsf(acc[t][r] * inv[r]);
      l1[r] += a;
      if (col == lab[r]) al[r] = a;
    }
  }
  // reduce across the 16 lanes sharing kg (cols)
#pragma unroll
  for (int r = 0; r < 4; ++r) {
#pragma unroll
    for (int off = 1; off < 16; off <<= 1) {
      l1[r] += __shfl_xor(l1[r], off);
      al[r] += __shfl_xor(al[r], off);
    }
  }

  float contrib = 0.f;
  if (m == 0) {
#pragma unroll
    for (int r = 0; r < 4; ++r) {
      if (lb[r]) contrib += (l1[r] - 2.f * al[r]) / fmaxf(l1[r], 1e-12f);
    }
  }
  // sum the 4 per-kgroup partials (lanes 0,16,32,48), one atomic per wave
  contrib += __shfl_xor(contrib, 16);
  contrib += __shfl_xor(contrib, 32);
  if (lane == 0) atomicAdd(out, contrib);
}

extern "C" void kernel_launch(void* const* d_in, const int* in_sizes, int n_in,
                              void* d_out, int out_size, void* d_ws, size_t ws_size,
                              hipStream_t stream) {
  const float* feats = (const float*)d_in[0];
  const float* centers = (const float*)d_in[1];
  const int* labels = (const int*)d_in[2];
  const int* labelled = (const int*)d_in[3];  // bool -> int32 per harness convention
  float* out = (float*)d_out;
  short* cnb = (short*)d_ws;  // [CPAD][DIMS] bf16 = 393216 B

  hipMemsetAsync(out, 0, sizeof(float) * out_size, stream);
  prep_centers_k<<<CPAD, 256, 0, stream>>>(centers, cnb);
  cos_loss_k<<<NROWS / 64, 256, 0, stream>>>(feats, cnb, labels, labelled, out);
}

// Round 3
// 111.540 us; speedup vs baseline: 1.1807x; 1.1807x over previous
//
#include <hip/hip_runtime.h>
#include <hip/hip_bf16.h>

// Problem constants (fixed by setup_inputs): B=32768, D=768, C=200.
#define NROWS 32768
#define DIMS  768
#define NC    200
#define CPAD  256   // pad centers to 256 zero rows -> no column masking needed
#define LDA   776   // 768 + 8 bf16 pad; 776*2=1552 B keeps 16-B alignment per row

typedef __attribute__((ext_vector_type(8))) short short8;  // 8 bf16 in 4 VGPRs
typedef __attribute__((ext_vector_type(4))) short short4v; // 4 bf16 = 8 B
typedef __attribute__((ext_vector_type(4))) float f32x4;

__device__ __forceinline__ short f2bfs(float f) {
  // round-to-nearest-even f32 -> bf16 bits
  union { float f; unsigned u; } x; x.f = f;
  unsigned u = x.u;
  unsigned r = u + 0x7fffu + ((u >> 16) & 1u);
  return (short)(r >> 16);
}

// Kernel 1: L2-normalize centers, write bf16 [CPAD][DIMS]; rows >= NC are zeros.
__global__ __launch_bounds__(256) void prep_centers_k(const float* __restrict__ centers,
                                                      short* __restrict__ cnb) {
  const int c = blockIdx.x;
  const int tid = threadIdx.x;
  if (c >= NC) {
    for (int d = tid; d < DIMS; d += 256) cnb[c * DIMS + d] = 0;
    return;
  }
  float ssq = 0.f;
  for (int d = tid; d < DIMS; d += 256) {
    float v = centers[c * DIMS + d];
    ssq += v * v;
  }
#pragma unroll
  for (int off = 32; off > 0; off >>= 1) ssq += __shfl_down(ssq, off);
  __shared__ float red[4];
  const int wid = tid >> 6, lane = tid & 63;
  if (lane == 0) red[wid] = ssq;
  __syncthreads();
  const float tot = red[0] + red[1] + red[2] + red[3];
  const float inv = 1.f / fmaxf(sqrtf(tot), 1e-8f);
  for (int d = tid; d < DIMS; d += 256) cnb[c * DIMS + d] = f2bfs(centers[c * DIMS + d] * inv);
}

// Kernel 2: block = 4 waves = 16 rows x 256 cols. A tile staged once in LDS (bf16),
// each wave owns 64 cols (4 MFMA tiles). Barrier-free K-loop.
// A frag (16x32 bf16): lane holds A[m][k], m=lane&15, k=(lane>>4)*8+j.
// B frag (32x16 bf16): lane holds B[k][n], n=lane&15, k=(lane>>4)*8+j.
// D frag: col=lane&15, row=(lane>>4)*4+reg.   [same verified mapping as round 2]
__global__ __launch_bounds__(256) void cos_loss_k(
    const float* __restrict__ feats,
    const short* __restrict__ cnb,
    const int* __restrict__ labels,
    const int* __restrict__ labelled,     // bool shipped as int32 by harness
    float* __restrict__ out) {
  const int tid = threadIdx.x;
  const int w = tid >> 6;      // wave id 0..3 -> column group (64 cols each)
  const int lane = tid & 63;
  const int m = lane & 15;
  const int kg = lane >> 4;    // k-group 0..3
  const int rowBase = blockIdx.x * 16;

  __shared__ short As[16][LDA];   // raw bf16 A tile (normalization applied in epilogue)
  __shared__ float invs[16];
  __shared__ float l1part[4][16];
  __shared__ float alpart[4][16];

  // ---- Stage A: thread -> row tid>>4, 16 threads/row, interleaved float4 cols ----
  {
    const int r = tid >> 4;       // 0..15
    const int c = tid & 15;       // 0..15
    const float* src = feats + (size_t)(rowBase + r) * DIMS;
    float ssq = 0.f;
#pragma unroll
    for (int j = 0; j < 12; ++j) {
      const int col = (c + j * 16) * 4;          // float index
      const float4 v = *(const float4*)(src + col);
      ssq += v.x * v.x + v.y * v.y + v.z * v.z + v.w * v.w;
      short4v s4;
      s4[0] = f2bfs(v.x); s4[1] = f2bfs(v.y); s4[2] = f2bfs(v.z); s4[3] = f2bfs(v.w);
      *(short4v*)(&As[r][col]) = s4;
    }
    // reduce ssq over the 16 threads of this row (low 4 lane bits)
#pragma unroll
    for (int off = 1; off < 16; off <<= 1) ssq += __shfl_xor(ssq, off);
    if (c == 0) invs[r] = 1.f / fmaxf(sqrtf(ssq), 1e-8f);
  }
  __syncthreads();

  // ---- Barrier-free K-loop: 1 LDS A-frag read + 4 global B loads + 4 MFMAs ----
  f32x4 acc[4];
#pragma unroll
  for (int tt = 0; tt < 4; ++tt) acc[tt] = (f32x4){0.f, 0.f, 0.f, 0.f};

  const short* ap = &As[m][kg * 8];
  const short* bp = cnb + (size_t)(w * 64 + m) * DIMS + kg * 8;

#pragma unroll
  for (int k0 = 0; k0 < DIMS; k0 += 32) {
    const short8 af = *(const short8*)(ap + k0);
#pragma unroll
    for (int tt = 0; tt < 4; ++tt) {
      const short8 bf = *(const short8*)(bp + (size_t)tt * 16 * DIMS + k0);
      acc[tt] = __builtin_amdgcn_mfma_f32_16x16x32_bf16(af, bf, acc[tt], 0, 0, 0);
    }
  }

  // ---- Epilogue ----
  float inv4[4];
  int lab[4], lb[4];
#pragma unroll
  for (int r = 0; r < 4; ++r) {
    const int row = kg * 4 + r;
    inv4[r] = invs[row];
    lab[r] = labels[rowBase + row];
    lb[r] = labelled[rowBase + row];
  }

  float l1[4] = {0.f, 0.f, 0.f, 0.f};
  float al[4] = {0.f, 0.f, 0.f, 0.f};
#pragma unroll
  for (int tt = 0; tt < 4; ++tt) {
    const int col = w * 64 + tt * 16 + m;
#pragma unroll
    for (int r = 0; r < 4; ++r) {
      const float a = fabsf(acc[tt][r] * inv4[r]);
      l1[r] += a;
      if (col == lab[r]) al[r] += a;
    }
  }
  // reduce across the 16 lanes sharing kg (column lanes)
#pragma unroll
  for (int r = 0; r < 4; ++r) {
#pragma unroll
    for (int off = 1; off < 16; off <<= 1) {
      l1[r] += __shfl_xor(l1[r], off);
      al[r] += __shfl_xor(al[r], off);
    }
  }
  if (m == 0) {
#pragma unroll
    for (int r = 0; r < 4; ++r) {
      l1part[w][kg * 4 + r] = l1[r];
      alpart[w][kg * 4 + r] = al[r];
    }
  }
  __syncthreads();

  if (tid < 16) {
    const int row = tid;
    const float L = l1part[0][row] + l1part[1][row] + l1part[2][row] + l1part[3][row];
    const float A = alpart[0][row] + alpart[1][row] + alpart[2][row] + alpart[3][row];
    float contrib = 0.f;
    if (labelled[rowBase + row]) contrib = (L - 2.f * A) / fmaxf(L, 1e-12f);
#pragma unroll
    for (int off = 1; off < 16; off <<= 1) contrib += __shfl_xor(contrib, off);
    if (tid == 0) atomicAdd(out, contrib);
  }
}

extern "C" void kernel_launch(void* const* d_in, const int* in_sizes, int n_in,
                              void* d_out, int out_size, void* d_ws, size_t ws_size,
                              hipStream_t stream) {
  const float* feats = (const float*)d_in[0];
  const float* centers = (const float*)d_in[1];
  const int* labels = (const int*)d_in[2];
  const int* labelled = (const int*)d_in[3];  // bool -> int32 per harness convention
  float* out = (float*)d_out;
  short* cnb = (short*)d_ws;  // [CPAD][DIMS] bf16 = 393216 B

  hipMemsetAsync(out, 0, sizeof(float) * out_size, stream);
  prep_centers_k<<<CPAD, 256, 0, stream>>>(centers, cnb);
  cos_loss_k<<<NROWS / 16, 256, 0, stream>>>(feats, cnb, labels, labelled, out);
}

// Round 4
// 41.028 us; speedup vs baseline: 3.2100x; 2.7187x over previous
//
#include <hip/hip_runtime.h>
#include <hip/hip_bf16.h>

// Problem constants (fixed by setup_inputs): B=32768, D=768, C=200.
#define NROWS 32768
#define DIMS  768
#define NC    200
#define CPAD  256      // centers padded to 256 zero rows
#define KSTEP 32       // K-tile per barrier step
#define NSTEP (DIMS / KSTEP)   // 24
#define ROWSB 64       // rows per block
#define LDT   40       // padded shorts per LDS tile row (80 B stride -> conflict-free frags)

typedef __attribute__((ext_vector_type(8))) short short8;  // 8 bf16 in 4 VGPRs
typedef __attribute__((ext_vector_type(4))) float f32x4;

__device__ __forceinline__ short f2bfs(float f) {
  union { float f; unsigned u; } x; x.f = f;
  unsigned u = x.u;
  unsigned r = u + 0x7fffu + ((u >> 16) & 1u);
  return (short)(r >> 16);
}

// Kernel 1: L2-normalize centers -> bf16 in K-step-blocked layout:
// element (c, d) -> cnb2[(d>>5)*CPAD*KSTEP + c*KSTEP + (d&31)]
// so each K-step's B-slice [256 cols][32 k] is one contiguous 16 KB chunk.
__global__ __launch_bounds__(256) void prep_centers_k(const float* __restrict__ centers,
                                                      short* __restrict__ cnb2) {
  const int c = blockIdx.x;
  const int tid = threadIdx.x;
  if (c >= NC) {
    for (int d = tid; d < DIMS; d += 256)
      cnb2[(d >> 5) * (CPAD * KSTEP) + c * KSTEP + (d & 31)] = 0;
    return;
  }
  float ssq = 0.f;
  for (int d = tid; d < DIMS; d += 256) {
    float v = centers[c * DIMS + d];
    ssq += v * v;
  }
#pragma unroll
  for (int off = 32; off > 0; off >>= 1) ssq += __shfl_down(ssq, off);
  __shared__ float red[4];
  const int wid = tid >> 6, lane = tid & 63;
  if (lane == 0) red[wid] = ssq;
  __syncthreads();
  const float tot = red[0] + red[1] + red[2] + red[3];
  const float inv = 1.f / fmaxf(sqrtf(tot), 1e-8f);
  for (int d = tid; d < DIMS; d += 256)
    cnb2[(d >> 5) * (CPAD * KSTEP) + c * KSTEP + (d & 31)] =
        f2bfs(centers[c * DIMS + d] * inv);
}

// Kernel 2: LDS-tiled GEMM. Block = 4 waves = 64 rows x 256 cols, K-step 32, dbuf.
// Wave w owns cols w*64..w*64+63 (wave tile 64x64, acc[4][4]).
// MFMA frag mapping (verified rounds 2-3): A lane = A[m][k], m=lane&15, k=kg*8+j;
// B lane = B[k][n], n=lane&15, k=kg*8+j; D: col=lane&15, row=kg*4+reg.
__global__ __launch_bounds__(256) void cos_loss_k(
    const float* __restrict__ feats,
    const short* __restrict__ cnb2,
    const int* __restrict__ labels,
    const int* __restrict__ labelled,
    float* __restrict__ out) {
  const int tid = threadIdx.x;
  const int w = tid >> 6;     // wave id = column group
  const int lane = tid & 63;
  const int m = lane & 15;
  const int kg = lane >> 4;
  const int rowBase = blockIdx.x * ROWSB;

  __shared__ short As[2][ROWSB][LDT];   // 10240 B
  __shared__ short Bs[2][CPAD][LDT];    // 40960 B
  __shared__ float invs[ROWSB];
  __shared__ int   labLds[ROWSB];
  __shared__ int   lblLds[ROWSB];
  __shared__ float l1part[4][ROWSB];
  __shared__ float alpart[4][ROWSB];

  if (tid < ROWSB) {
    labLds[tid] = labels[rowBase + tid];
    lblLds[tid] = labelled[rowBase + tid];
  }

  // A staging map: row = tid>>2 (4 thr/row), koff = (tid&3)*8 floats
  const int arow = tid >> 2;
  const int akoff = (tid & 3) * 8;
  const float* asrc = feats + (size_t)(rowBase + arow) * DIMS + akoff;
  // B staging map: thread tid copies col=tid's 32 k-shorts (64 B contiguous in cnb2)
  const short* bsrc = cnb2 + tid * KSTEP;

  f32x4 acc[4][4];
#pragma unroll
  for (int mi = 0; mi < 4; ++mi)
#pragma unroll
    for (int ni = 0; ni < 4; ++ni) acc[mi][ni] = (f32x4){0.f, 0.f, 0.f, 0.f};

  float ssq = 0.f;
  float4 pva, pvb;            // A prefetch regs
  short8 pb0, pb1;            // B prefetch regs (32 shorts = 4x short8 -> use 4)
  short8 pb2, pb3;

  // ---- prologue: stage step 0 ----
  pva = *(const float4*)(asrc);
  pvb = *(const float4*)(asrc + 4);
  pb0 = *(const short8*)(bsrc + 0);
  pb1 = *(const short8*)(bsrc + 8);
  pb2 = *(const short8*)(bsrc + 16);
  pb3 = *(const short8*)(bsrc + 24);
  {
    ssq += pva.x*pva.x + pva.y*pva.y + pva.z*pva.z + pva.w*pva.w;
    ssq += pvb.x*pvb.x + pvb.y*pvb.y + pvb.z*pvb.z + pvb.w*pvb.w;
    short8 s;
    s[0]=f2bfs(pva.x); s[1]=f2bfs(pva.y); s[2]=f2bfs(pva.z); s[3]=f2bfs(pva.w);
    s[4]=f2bfs(pvb.x); s[5]=f2bfs(pvb.y); s[6]=f2bfs(pvb.z); s[7]=f2bfs(pvb.w);
    *(short8*)(&As[0][arow][akoff]) = s;
    *(short8*)(&Bs[0][tid][0])  = pb0;
    *(short8*)(&Bs[0][tid][8])  = pb1;
    *(short8*)(&Bs[0][tid][16]) = pb2;
    *(short8*)(&Bs[0][tid][24]) = pb3;
  }
  __syncthreads();

  // ---- main loop: one barrier per K-step, dbuf, loads issued before compute ----
#pragma unroll 2
  for (int ks = 0; ks < NSTEP; ++ks) {
    const int cur = ks & 1, nxt = cur ^ 1;
    if (ks < NSTEP - 1) {
      const int k0 = (ks + 1) * KSTEP;
      pva = *(const float4*)(asrc + k0);
      pvb = *(const float4*)(asrc + k0 + 4);
      const short* bs = bsrc + (size_t)(ks + 1) * (CPAD * KSTEP);
      pb0 = *(const short8*)(bs + 0);
      pb1 = *(const short8*)(bs + 8);
      pb2 = *(const short8*)(bs + 16);
      pb3 = *(const short8*)(bs + 24);
    }
    // compute on cur
    {
      short8 af[4], bf[4];
#pragma unroll
      for (int mi = 0; mi < 4; ++mi)
        af[mi] = *(const short8*)(&As[cur][mi * 16 + m][kg * 8]);
#pragma unroll
      for (int ni = 0; ni < 4; ++ni)
        bf[ni] = *(const short8*)(&Bs[cur][w * 64 + ni * 16 + m][kg * 8]);
#pragma unroll
      for (int mi = 0; mi < 4; ++mi)
#pragma unroll
        for (int ni = 0; ni < 4; ++ni)
          acc[mi][ni] = __builtin_amdgcn_mfma_f32_16x16x32_bf16(af[mi], bf[ni], acc[mi][ni], 0, 0, 0);
    }
    if (ks < NSTEP - 1) {
      ssq += pva.x*pva.x + pva.y*pva.y + pva.z*pva.z + pva.w*pva.w;
      ssq += pvb.x*pvb.x + pvb.y*pvb.y + pvb.z*pvb.z + pvb.w*pvb.w;
      short8 s;
      s[0]=f2bfs(pva.x); s[1]=f2bfs(pva.y); s[2]=f2bfs(pva.z); s[3]=f2bfs(pva.w);
      s[4]=f2bfs(pvb.x); s[5]=f2bfs(pvb.y); s[6]=f2bfs(pvb.z); s[7]=f2bfs(pvb.w);
      *(short8*)(&As[nxt][arow][akoff]) = s;
      *(short8*)(&Bs[nxt][tid][0])  = pb0;
      *(short8*)(&Bs[nxt][tid][8])  = pb1;
      *(short8*)(&Bs[nxt][tid][16]) = pb2;
      *(short8*)(&Bs[nxt][tid][24]) = pb3;
    }
    __syncthreads();
  }

  // ---- row inverse norms (fp32, from features) ----
  ssq += __shfl_xor(ssq, 1);
  ssq += __shfl_xor(ssq, 2);
  if ((tid & 3) == 0) invs[arow] = 1.f / fmaxf(sqrtf(ssq), 1e-8f);
  __syncthreads();

  // ---- epilogue: per-row l1 and label-|cos| ----
#pragma unroll
  for (int mi = 0; mi < 4; ++mi) {
    float l1r[4] = {0.f, 0.f, 0.f, 0.f};
    float alr[4] = {0.f, 0.f, 0.f, 0.f};
    float iv[4];
    int labr[4];
#pragma unroll
    for (int r = 0; r < 4; ++r) {
      const int row = mi * 16 + kg * 4 + r;
      iv[r] = invs[row];
      labr[r] = labLds[row];
    }
#pragma unroll
    for (int ni = 0; ni < 4; ++ni) {
      const int col = w * 64 + ni * 16 + m;
#pragma unroll
      for (int r = 0; r < 4; ++r) {
        const float a = fabsf(acc[mi][ni][r] * iv[r]);
        l1r[r] += a;
        if (col == labr[r]) alr[r] += a;
      }
    }
#pragma unroll
    for (int r = 0; r < 4; ++r) {
#pragma unroll
      for (int off = 1; off < 16; off <<= 1) {
        l1r[r] += __shfl_xor(l1r[r], off);
        alr[r] += __shfl_xor(alr[r], off);
      }
    }
    if (m == 0) {
#pragma unroll
      for (int r = 0; r < 4; ++r) {
        l1part[w][mi * 16 + kg * 4 + r] = l1r[r];
        alpart[w][mi * 16 + kg * 4 + r] = alr[r];
      }
    }
  }
  __syncthreads();

  if (tid < ROWSB) {
    const float L = l1part[0][tid] + l1part[1][tid] + l1part[2][tid] + l1part[3][tid];
    const float A = alpart[0][tid] + alpart[1][tid] + alpart[2][tid] + alpart[3][tid];
    float c = lblLds[tid] ? (L - 2.f * A) / fmaxf(L, 1e-12f) : 0.f;
#pragma unroll
    for (int off = 1; off < 64; off <<= 1) c += __shfl_xor(c, off);
    if (tid == 0) atomicAdd(out, c);
  }
}

extern "C" void kernel_launch(void* const* d_in, const int* in_sizes, int n_in,
                              void* d_out, int out_size, void* d_ws, size_t ws_size,
                              hipStream_t stream) {
  const float* feats = (const float*)d_in[0];
  const float* centers = (const float*)d_in[1];
  const int* labels = (const int*)d_in[2];
  const int* labelled = (const int*)d_in[3];
  float* out = (float*)d_out;
  short* cnb2 = (short*)d_ws;  // [24][256][32] bf16 = 393216 B

  hipMemsetAsync(out, 0, sizeof(float) * out_size, stream);
  prep_centers_k<<<CPAD, 256, 0, stream>>>(centers, cnb2);
  cos_loss_k<<<NROWS / ROWSB, 256, 0, stream>>>(feats, cnb2, labels, labelled, out);
}